// Round 12
// baseline (379.529 us; speedup 1.0000x reference)
//
#include <hip/hip_runtime.h>
#include <math.h>

#define NEG_SLOPE 0.2f

constexpr int F_IN  = 128;
constexpr int HC1   = 256;  // H*HID
constexpr int HC2   = 160;  // H*CLS
constexpr int NHEAD = 4;
constexpr int EB    = 2048; // edges per level-1 block
constexpr int NPB   = 256;  // nodes per bucket (== scan block size -> count+scan fuse)
constexpr int BCAP  = 8192; // bucket capacity (avg 4083 @ E=800k; +64 sigma safe)

typedef _Float16 h8v __attribute__((ext_vector_type(8)));
typedef _Float16 h4v __attribute__((ext_vector_type(4)));
typedef _Float16 h2v __attribute__((ext_vector_type(2)));
typedef float f4v __attribute__((ext_vector_type(4)));

// f32 += f16(lo/hi of packed) * f32 — single VOP3P instruction
#define FMIX_LO(acc, pk, wt) \
    asm("v_fma_mix_f32 %0, %1, %2, %0 op_sel:[0,0,0] op_sel_hi:[1,0,0]" \
        : "+v"(acc) : "v"(pk), "v"(wt))
#define FMIX_HI(acc, pk, wt) \
    asm("v_fma_mix_f32 %0, %1, %2, %0 op_sel:[1,0,0] op_sel_hi:[1,0,0]" \
        : "+v"(acc) : "v"(pk), "v"(wt))

__device__ __forceinline__ int edge_val(const void* p, int m64, long long i) {
    if (m64) return (int)((const long long*)p)[i];
    return ((const int*)p)[i];
}

// ---------------- dispatch 1: edge dtype detect (+ zero stats) ----------------
__global__ void detect_kernel(const unsigned int* __restrict__ ei_words, int* __restrict__ mode,
                              float* __restrict__ stats) {
    stats[threadIdx.x] = 0.f;  // 256 threads zero 256 floats (sum|sumsq)
    __shared__ unsigned int red[256];
    unsigned int v = 0;
    for (int i = 1 + 2 * (int)threadIdx.x; i < 4096; i += 512) v |= ei_words[i];
    red[threadIdx.x] = v;
    __syncthreads();
    for (int off = 128; off > 0; off >>= 1) {
        if (threadIdx.x < off) red[threadIdx.x] |= red[threadIdx.x + off];
        __syncthreads();
    }
    if (threadIdx.x == 0) *mode = (red[0] == 0u) ? 1 : 0;
}

// ---------------- dispatch 2 (fused): bucket-hist | colstats | convert_w ----------------
__global__ __launch_bounds__(256) void fused_pre_kernel(
    const void* __restrict__ ei, const int* __restrict__ mode, int E, int nbuck, int nblk1,
    int* __restrict__ hist, const float* __restrict__ x, float* __restrict__ stats, int N,
    const float* __restrict__ W1, const float* __restrict__ aS1, const float* __restrict__ aD1,
    _Float16* __restrict__ B1x, const float* __restrict__ W2, const float* __restrict__ aS2,
    const float* __restrict__ aD2, _Float16* __restrict__ B2x, int nbStats) {
    int b = blockIdx.x;
    if (b < nblk1) {
        // ---- level-1 histogram (bucket = dst >> 8) ----
        __shared__ int lh[256];
        for (int i = threadIdx.x; i < nbuck; i += 256) lh[i] = 0;
        __syncthreads();
        int m = *mode;
        long long e0 = (long long)b * EB;
#pragma unroll
        for (int k = 0; k < EB / 256; k++) {
            long long e = e0 + (int)threadIdx.x + k * 256;
            if (e < E) {
                int d = edge_val(ei, m, (long long)E + e);
                atomicAdd(&lh[d >> 8], 1);
            }
        }
        __syncthreads();
        for (int i = threadIdx.x; i < nbuck; i += 256) hist[(size_t)i * nblk1 + b] = lh[i];
    } else if (b < nblk1 + nbStats) {
        // ---- colstats: float4 loads, 32 iters/thread, LDS-reduce 8 row groups ----
        int t = (int)threadIdx.x;
        int c = t & 31;   // handles cols 4c..4c+3
        int g = t >> 5;   // row subgroup 0..7
        int r0 = (b - nblk1) * 256;
        int rend = min(r0 + 256, N);
        f4v s = {0.f, 0.f, 0.f, 0.f}, q = {0.f, 0.f, 0.f, 0.f};
        for (int r = r0 + g; r < rend; r += 8) {
            f4v v = *(const f4v*)&x[(long)r * F_IN + 4 * c];
            s += v;
            q += v * v;
        }
        __shared__ f4v sh4[256];
        sh4[t] = s;
        __syncthreads();
        if (t < 32) {
            f4v a = sh4[t];
            for (int g2 = 1; g2 < 8; g2++) a += sh4[g2 * 32 + t];
            atomicAdd(&stats[4 * t + 0], a[0]);
            atomicAdd(&stats[4 * t + 1], a[1]);
            atomicAdd(&stats[4 * t + 2], a[2]);
            atomicAdd(&stats[4 * t + 3], a[3]);
        }
        __syncthreads();
        sh4[t] = q;
        __syncthreads();
        if (t < 32) {
            f4v a = sh4[t];
            for (int g2 = 1; g2 < 8; g2++) a += sh4[g2 * 32 + t];
            atomicAdd(&stats[128 + 4 * t + 0], a[0]);
            atomicAdd(&stats[128 + 4 * t + 1], a[1]);
            atomicAdd(&stats[128 + 4 * t + 2], a[2]);
            atomicAdd(&stats[128 + 4 * t + 3], a[3]);
        }
    } else {
        // ---- convert weights -> fp16 transposed + att columns ----
        constexpr int T1 = (HC1 + 16) * F_IN;
        constexpr int T2 = (HC2 + 16) * HC1;
        int idx = (b - nblk1 - nbStats) * 256 + (int)threadIdx.x;
        if (idx < T1) {
            int n = idx / F_IN, k = idx - n * F_IN;
            float v = 0.f;
            if (n < HC1) {
                v = W1[k * HC1 + n];
            } else {
                int n2 = n - HC1;
                if (n2 < 8) {
                    int hd = n2 & 3;
                    const float* a = (n2 < 4) ? aS1 : aD1;
                    for (int c = 0; c < 64; c++) v += W1[k * HC1 + hd * 64 + c] * a[hd * 64 + c];
                }
            }
            B1x[n * F_IN + k] = (_Float16)v;
        } else if (idx < T1 + T2) {
            int i2 = idx - T1;
            int n = i2 / HC1, k = i2 - n * HC1;
            float v = 0.f;
            if (n < HC2) {
                v = W2[k * HC2 + n];
            } else {
                int n2 = n - HC2;
                if (n2 < 8) {
                    int hd = n2 & 3;
                    const float* a = (n2 < 4) ? aS2 : aD2;
                    for (int c = 0; c < 40; c++) v += W2[k * HC2 + hd * 40 + c] * a[hd * 40 + c];
                }
            }
            B2x[n * HC1 + k] = (_Float16)v;
        }
    }
}

// ---------------- dispatch 3 (fused): standardize | bucket col-scan ----------------
__global__ __launch_bounds__(256) void fused_mid_kernel(
    const float* __restrict__ x, const float* __restrict__ stats, _Float16* __restrict__ xs,
    int total4, float invN, float invN1, const int* __restrict__ hist,
    int* __restrict__ colBaseT, int* __restrict__ bucketTotal, int nbuck, int nblk1,
    int nbStd) {
    int b = blockIdx.x;
    if (b < nbStd) {
        int i = b * 256 + (int)threadIdx.x;
        if (i >= total4) return;
        int c = (i * 4) & (F_IN - 1);
        float4 s4 = *(const float4*)&stats[c];
        float4 q4 = *(const float4*)&stats[128 + c];
        float4 v = ((const float4*)x)[i];
        h4v o;
        o[0] = (_Float16)((v.x - s4.x * invN) / sqrtf((q4.x - s4.x * s4.x * invN) * invN1));
        o[1] = (_Float16)((v.y - s4.y * invN) / sqrtf((q4.y - s4.y * s4.y * invN) * invN1));
        o[2] = (_Float16)((v.z - s4.z * invN) / sqrtf((q4.z - s4.z * s4.z * invN) * invN1));
        o[3] = (_Float16)((v.w - s4.w * invN) / sqrtf((q4.w - s4.w * s4.w * invN) * invN1));
        ((h4v*)xs)[i] = o;
    } else {
        // col-scan: exclusive prefix over blocks of hist[bb][*]; write transposed
        int bb = b - nbStd;
        int t = (int)threadIdx.x;
        __shared__ int sh[512];
        __shared__ int wsum[4];
        for (int i = t; i < nblk1; i += 256) sh[i] = hist[(size_t)bb * nblk1 + i];
        __syncthreads();
        int carry = 0;
        for (int base = 0; base < nblk1; base += 256) {
            int idx = base + t;
            int v = (idx < nblk1) ? sh[idx] : 0;
            int lane = t & 63, w = t >> 6;
            int xv = v;
#pragma unroll
            for (int d = 1; d < 64; d <<= 1) {
                int y = __shfl_up(xv, d);
                if (lane >= d) xv += y;
            }
            if (lane == 63) wsum[w] = xv;
            __syncthreads();
            int wb = 0;
            for (int k = 0; k < w; k++) wb += wsum[k];
            int excl = xv - v + wb + carry;
            if (idx < nblk1) colBaseT[(size_t)idx * nbuck + bb] = excl;
            carry += wsum[0] + wsum[1] + wsum[2] + wsum[3];
            __syncthreads();
        }
        if (t == 0) bucketTotal[bb] = carry;
    }
}

// ---------------- dispatch 4: level-1 scatter into bucket regions ----------------
__global__ __launch_bounds__(256) void scatter1_kernel(const void* __restrict__ ei,
                                                       const int* __restrict__ mode, int E,
                                                       int nbuck,
                                                       const int* __restrict__ colBaseT,
                                                       int* __restrict__ bucketEdges) {
    __shared__ int cur[256];
    int b = blockIdx.x;
    for (int i = threadIdx.x; i < nbuck; i += 256)
        cur[i] = colBaseT[(size_t)b * nbuck + i];
    __syncthreads();
    int m = *mode;
    long long e0 = (long long)b * EB;
#pragma unroll
    for (int k = 0; k < EB / 256; k++) {
        long long e = e0 + (int)threadIdx.x + k * 256;
        if (e < E) {
            int s = edge_val(ei, m, e);
            int d = edge_val(ei, m, (long long)E + e);
            int bk = d >> 8;
            int r = atomicAdd(&cur[bk], 1);  // LDS returning atomic (fast)
            bucketEdges[(size_t)bk * BCAP + r] = s | ((d & (NPB - 1)) << 16);
        }
    }
}

// ---------------- dispatch 5 (fused): per-bucket node counts + local scan ------------
__global__ __launch_bounds__(256) void bucket_count_scan_kernel(
    const int* __restrict__ bucketEdges, const int* __restrict__ bucketTotal,
    int* __restrict__ offsets, int* __restrict__ blocksum, int N) {
    __shared__ int c[NPB];
    int b = blockIdx.x, t = threadIdx.x;
    c[t] = 0;
    __syncthreads();
    int cnt = bucketTotal[b];
    const int* be = bucketEdges + (size_t)b * BCAP;
    for (int i = t; i < cnt; i += 256) atomicAdd(&c[(be[i] >> 16) & (NPB - 1)], 1);
    __syncthreads();
    int node = b * NPB + t;
    int v = (node < N) ? c[t] + 1 : 0;  // +1 self loop
    int lane = t & 63, w = t >> 6;
    int xv = v;
#pragma unroll
    for (int d = 1; d < 64; d <<= 1) {
        int y = __shfl_up(xv, d);
        if (lane >= d) xv += y;
    }
    __shared__ int wsum[4];
    if (lane == 63) wsum[w] = xv;
    __syncthreads();
    int base = 0;
    for (int k = 0; k < w; k++) base += wsum[k];
    int incl = xv + base;
    if (node < N) offsets[node + 1] = incl;
    if (t == 255) blocksum[b] = incl;
}

// ---------------- dispatch 6: scan_add ----------------
__global__ void scan_add_kernel(const int* __restrict__ blocksum, int* __restrict__ offsets, int N,
                                int nb) {
    int t = threadIdx.x;
    int v = (t < nb) ? blocksum[t] : 0;
    int lane = t & 63, w = t >> 6;
    int x = v;
#pragma unroll
    for (int d = 1; d < 64; d <<= 1) {
        int y = __shfl_up(x, d);
        if (lane >= d) x += y;
    }
    __shared__ int wsum[4];
    __shared__ int excl[256];
    if (lane == 63) wsum[w] = x;
    __syncthreads();
    int base = 0;
    for (int k = 0; k < w; k++) base += wsum[k];
    excl[t] = x + base - v;
    __syncthreads();
    int myb = excl[blockIdx.x];
    int i = blockIdx.x * 256 + t;
    if (i < N) offsets[i + 1] += myb;
    if (i == 0) offsets[0] = 0;
}

// ---------------- att1 mini-GEMM: as1/ad1 = xs @ (W1·att) (8 cols) ----------------
__device__ __forceinline__ void att1_body(int blk, const _Float16* __restrict__ A,
                                          const _Float16* __restrict__ Batt,
                                          float* __restrict__ as_, float* __restrict__ ad_,
                                          int M) {
    constexpr int KT = F_IN / 32;  // 4
    int w = threadIdx.x >> 6;
    int l = threadIdx.x & 63;
    int quad = l >> 4, lan = l & 15;
    int row = blk * 64 + w * 16 + lan;
    int arow = min(row, M - 1);
    const _Float16* Aptr = A + (long)arow * F_IN + quad * 8;
    h8v afr[KT], bfr[KT];
#pragma unroll
    for (int k0 = 0; k0 < KT; k0++) afr[k0] = *(const h8v*)(Aptr + k0 * 32);
#pragma unroll
    for (int k0 = 0; k0 < KT; k0++)
        bfr[k0] = *(const h8v*)(Batt + (long)lan * F_IN + k0 * 32 + quad * 8);
    f4v acc = {0.f, 0.f, 0.f, 0.f};
#pragma unroll
    for (int k0 = 0; k0 < KT; k0++)
        acc = __builtin_amdgcn_mfma_f32_16x16x32_f16(afr[k0], bfr[k0], acc, 0, 0, 0);
    int orow = blk * 64 + w * 16 + quad * 4;
#pragma unroll
    for (int r = 0; r < 4; r++) {
        int gr = orow + r;
        if (gr < M) {
            float av = acc[r];
            if (lan < 4)
                as_[gr * 4 + lan] = av;
            else if (lan < 8)
                ad_[gr * 4 + lan - 4] = av;
        }
    }
}

// ---------------- dispatch 7 (fused): csr-scatter | att1 ----------------
__global__ __launch_bounds__(256) void fused_csr_att1_kernel(
    const int* __restrict__ bucketEdges, const int* __restrict__ bucketTotal,
    const int* __restrict__ offsets, int* __restrict__ csr, int N, int nbuck,
    const _Float16* __restrict__ xs, const _Float16* __restrict__ B1x,
    float* __restrict__ as_, float* __restrict__ ad_) {
    int b = blockIdx.x;
    if (b < nbuck) {
        __shared__ int cur[NPB];
        int t = threadIdx.x;
        int node = b * NPB + t;
        if (node < N) {
            int off = offsets[node];
            csr[off] = node;  // self loop at slot 0
            cur[t] = off + 1;
        }
        __syncthreads();
        int cnt = bucketTotal[b];
        const int* be = bucketEdges + (size_t)b * BCAP;
        for (int i = t; i < cnt; i += 256) {
            int v = be[i];
            int pos = atomicAdd(&cur[(v >> 16) & (NPB - 1)], 1);  // LDS returning atomic
            csr[pos] = v & 0xFFFF;
        }
    } else {
        att1_body(b - nbuck, xs, B1x + (size_t)HC1 * F_IN, as_, ad_, N);
    }
}

// ---------------- dispatch 8 (fused): layer-1 aggregate (xs-space) + per-node GEMM ----
// Phase 1 (per wave = per node): R8 aggregation, 8 accumulators (4 heads x 2ch/lane);
// normalized result -> LDS agg_sh[node][head][128] (4KB).
// Phase 2 (per thread = output channel c): o1[n][c] = relu(dot128(agg[n][c/64], W1[:,c]) + b1[c]).
// Kills the 51.2MB aggx write + 51.2MB gemm1b re-read; W1 cols stream from L2-hot B1x.
__global__ __launch_bounds__(256, 4) void aggregate_x4g_kernel(
    const _Float16* __restrict__ xs, const float* __restrict__ a_src,
    const float* __restrict__ a_dst, const int* __restrict__ offsets,
    const int* __restrict__ csr_src, const _Float16* __restrict__ B1x,
    const float* __restrict__ bias, _Float16* __restrict__ o1, int Ntot) {
    int w = threadIdx.x >> 6, l = threadIdx.x & 63;
    int node = blockIdx.x * 4 + w;
    const bool valid = (node < Ntot);

    __shared__ __align__(16) int sidx_sh[4][64];     // byte offsets into xs (row = 256B)
    __shared__ __align__(16) float ew_sh[4][64][4];  // per-edge per-head exp weights
    __shared__ __align__(16) _Float16 agg_sh[4][NHEAD][F_IN];  // 4KB staging

    float ds0 = 0.f, ds1 = 0.f, ds2 = 0.f, ds3 = 0.f;
    float a00 = 0.f, a01 = 0.f, a10 = 0.f, a11 = 0.f;
    float a20 = 0.f, a21 = 0.f, a30 = 0.f, a31 = 0.f;

#define X4_EDGE(p, wv)                                   \
    do {                                                 \
        FMIX_LO(a00, p, wv.x); FMIX_HI(a01, p, wv.x);    \
        FMIX_LO(a10, p, wv.y); FMIX_HI(a11, p, wv.y);    \
        FMIX_LO(a20, p, wv.z); FMIX_HI(a21, p, wv.z);    \
        FMIX_LO(a30, p, wv.w); FMIX_HI(a31, p, wv.w);    \
    } while (0)

    if (valid) {
        int start = offsets[node], deg = offsets[node + 1] - start;
        float4 adv = ((const float4*)a_dst)[node];
        const char* hbl = (const char*)xs + 4 * l;  // this lane's 2-channel slice

        for (int base = 0; base < deg; base += 64) {
            int cnt = min(64, deg - base);
            if (l < cnt) {
                int s = csr_src[start + base + l];
                sidx_sh[w][l] = s * (F_IN * 2);
                float4 av = ((const float4*)a_src)[s];
                float e0 = av.x + adv.x, e1 = av.y + adv.y, e2 = av.z + adv.z,
                      e3 = av.w + adv.w;
                e0 = fmaxf(e0, NEG_SLOPE * e0);
                e1 = fmaxf(e1, NEG_SLOPE * e1);
                e2 = fmaxf(e2, NEG_SLOPE * e2);
                e3 = fmaxf(e3, NEG_SLOPE * e3);
                float w0 = __expf(e0), w1 = __expf(e1), w2 = __expf(e2), w3 = __expf(e3);
                *(float4*)ew_sh[w][l] = make_float4(w0, w1, w2, w3);
                ds0 += w0;
                ds1 += w1;
                ds2 += w2;
                ds3 += w3;
            }
            int j = 0;
            for (; j + 3 < cnt; j += 4) {
                int4 o4 = *(const int4*)&sidx_sh[w][j];
                float4 wa = *(const float4*)ew_sh[w][j + 0];
                float4 wb = *(const float4*)ew_sh[w][j + 1];
                float4 wc = *(const float4*)ew_sh[w][j + 2];
                float4 wd = *(const float4*)ew_sh[w][j + 3];
                int p0 = *(const int*)(hbl + o4.x);
                int p1 = *(const int*)(hbl + o4.y);
                int p2 = *(const int*)(hbl + o4.z);
                int p3 = *(const int*)(hbl + o4.w);
                X4_EDGE(p0, wa);
                X4_EDGE(p1, wb);
                X4_EDGE(p2, wc);
                X4_EDGE(p3, wd);
            }
            for (; j < cnt; j++) {
                int off = sidx_sh[w][j];
                float4 wa = *(const float4*)ew_sh[w][j];
                int p0 = *(const int*)(hbl + off);
                X4_EDGE(p0, wa);
            }
        }

#pragma unroll
        for (int off = 1; off < 64; off <<= 1) {
            ds0 += __shfl_xor(ds0, off);
            ds1 += __shfl_xor(ds1, off);
            ds2 += __shfl_xor(ds2, off);
            ds3 += __shfl_xor(ds3, off);
        }

        float i0 = 1.0f / ds0, i1 = 1.0f / ds1, i2 = 1.0f / ds2, i3 = 1.0f / ds3;
        h2v hv;
        hv[0] = (_Float16)(a00 * i0);
        hv[1] = (_Float16)(a01 * i0);
        *(h2v*)&agg_sh[w][0][2 * l] = hv;
        hv[0] = (_Float16)(a10 * i1);
        hv[1] = (_Float16)(a11 * i1);
        *(h2v*)&agg_sh[w][1][2 * l] = hv;
        hv[0] = (_Float16)(a20 * i2);
        hv[1] = (_Float16)(a21 * i2);
        *(h2v*)&agg_sh[w][2][2 * l] = hv;
        hv[0] = (_Float16)(a30 * i3);
        hv[1] = (_Float16)(a31 * i3);
        *(h2v*)&agg_sh[w][3][2 * l] = hv;
    }
#undef X4_EDGE

    __syncthreads();

    // ---- phase 2: per-node matvec vs W1 (B1x is W1 transposed: row c = W1[:,c]) ----
    int c = threadIdx.x;  // output channel 0..255
    int hd2 = c >> 6;     // head = c / 64
    const _Float16* wcol = B1x + (size_t)c * F_IN;
    h8v wv[16];
#pragma unroll
    for (int kk = 0; kk < 16; kk++) wv[kk] = *(const h8v*)(wcol + kk * 8);
    float bc = bias[c];
#pragma unroll
    for (int n = 0; n < 4; n++) {
        int gn = blockIdx.x * 4 + n;
        if (gn < Ntot) {
            float acc = 0.f;
#pragma unroll
            for (int kk = 0; kk < 16; kk++) {
                h8v av = *(const h8v*)&agg_sh[n][hd2][kk * 8];
#pragma unroll
                for (int e = 0; e < 8; e++) acc += (float)av[e] * (float)wv[kk][e];
            }
            o1[(size_t)gn * HC1 + c] = (_Float16)fmaxf(acc + bc, 0.f);
        }
    }
}

// ---------------- dispatch 9: gemm2(+att2) with fragment-linear LDS-staged B ----------
template <int CT0, int CT1>
__device__ __forceinline__ void gemm2_lds_body(int blk, const _Float16* __restrict__ A,
                                               const _Float16* __restrict__ Btx,
                                               _Float16* Bs, _Float16* __restrict__ C_,
                                               float* __restrict__ as_, float* __restrict__ ad_,
                                               int M) {
    constexpr int NT = HC2 / 16;   // 10
    constexpr int NC = CT1 - CT0;  // 5 or 6
    constexpr int KT = HC1 / 32;   // 8
    int t = threadIdx.x;
    int w = t >> 6, l = t & 63;
    int quad = l >> 4, lan = l & 15;
    int row = blk * 64 + w * 16 + lan;
    int arow = min(row, M - 1);
    const _Float16* Aptr = A + (long)arow * HC1 + quad * 8;
    h8v afr[KT];
#pragma unroll
    for (int k0 = 0; k0 < KT; k0++) afr[k0] = *(const h8v*)(Aptr + k0 * 32);
#pragma unroll
    for (int jj = 0; jj < NC * KT * 64 / 256; jj++) {  // 10 or 12 iters
        int j = jj * 256 + t;
        int cik = j >> 6;
        int k0_ = cik % KT, ci_ = cik / KT;
        int jl = j & 63;
        const _Float16* src =
            Btx + (long)((CT0 + ci_) * 16 + (jl & 15)) * HC1 + k0_ * 32 + (jl >> 4) * 8;
        *(h8v*)(Bs + (size_t)j * 8) = *(const h8v*)src;
    }
    __syncthreads();
    f4v acc[NC] = {};
#pragma unroll
    for (int k0 = 0; k0 < KT; k0++)
#pragma unroll
        for (int ci = 0; ci < NC; ci++) {
            h8v bf = *(const h8v*)(Bs + ((size_t)(ci * KT + k0) * 64 + l) * 8);
            acc[ci] = __builtin_amdgcn_mfma_f32_16x16x32_f16(afr[k0], bf, acc[ci], 0, 0, 0);
        }
    int orow = blk * 64 + w * 16 + quad * 4;
#pragma unroll
    for (int r = 0; r < 4; r++) {
        int gr = orow + r;
        if (gr < M) {
            _Float16* out = C_ + (long)gr * HC2 + lan;
#pragma unroll
            for (int ci = 0; ci < NC; ci++) {
                int ct = CT0 + ci;
                if (ct < NT) out[ct * 16] = (_Float16)acc[ci][r];
            }
            if (CT1 == NT + 1) {
                float av = acc[NC - 1][r];
                if (lan < 4)
                    as_[gr * 4 + lan] = av;
                else if (lan < 8)
                    ad_[gr * 4 + lan - 4] = av;
            }
        }
    }
}

__global__ __launch_bounds__(256, 3) void gemm2_kernel(const _Float16* __restrict__ A,
                                                       const _Float16* __restrict__ B2x,
                                                       _Float16* __restrict__ C_,
                                                       float* __restrict__ as_,
                                                       float* __restrict__ ad_, int M) {
    __shared__ __align__(16) _Float16 Bs[6 * 8 * 64 * 8];  // 48KB (odd half size)
    int blk = blockIdx.x >> 1;
    if (blockIdx.x & 1)
        gemm2_lds_body<5, 11>(blk, A, B2x, Bs, C_, as_, ad_, M);  // tiles 5-9 + att
    else
        gemm2_lds_body<0, 5>(blk, A, B2x, Bs, C_, as_, ad_, M);   // tiles 0-4
}

// ---------------- dispatch 10: layer-2 aggregate (R8 compiler-scheduled form) ----------
template <int HC, bool RELU, typename OutT>
__global__ __launch_bounds__(256, 4) void aggregate_kernel(
    const _Float16* __restrict__ hb, const float* __restrict__ a_src,
    const float* __restrict__ a_dst, const int* __restrict__ offsets,
    const int* __restrict__ csr_src, const float* __restrict__ bias, OutT* __restrict__ out,
    int Ntot) {
    constexpr int ACT = HC / 4;       // active gather lanes (64 or 40)
    constexpr int CHPH = HC / NHEAD;  // channels per head
    constexpr bool FULL = (ACT == 64);
    int w = threadIdx.x >> 6, l = threadIdx.x & 63;
    int node = blockIdx.x * 4 + w;
    if (node >= Ntot) return;  // wave-uniform exit

    __shared__ __align__(16) int sidx_sh[4][64];     // byte offsets into hb
    __shared__ __align__(16) float ew_sh[4][64][4];  // per-edge per-head exp weights

    int start = offsets[node], end = offsets[node + 1];
    int deg = end - start;
    float4 adv = ((const float4*)a_dst)[node];
    const int hd = min((4 * l) / CHPH, 3);
    const char* hbl = (const char*)hb + 8 * l;  // this lane's 4-channel slice

    float ds0 = 0.f, ds1 = 0.f, ds2 = 0.f, ds3 = 0.f;
    float a0 = 0.f, a1 = 0.f, a2 = 0.f, a3 = 0.f;

    for (int base = 0; base < deg; base += 64) {
        int cnt = min(64, deg - base);
        if (l < cnt) {
            int s = csr_src[start + base + l];
            sidx_sh[w][l] = s * (HC * 2);
            float4 av = ((const float4*)a_src)[s];
            float e0 = av.x + adv.x, e1 = av.y + adv.y, e2 = av.z + adv.z, e3 = av.w + adv.w;
            e0 = fmaxf(e0, NEG_SLOPE * e0);
            e1 = fmaxf(e1, NEG_SLOPE * e1);
            e2 = fmaxf(e2, NEG_SLOPE * e2);
            e3 = fmaxf(e3, NEG_SLOPE * e3);
            float w0 = __expf(e0), w1 = __expf(e1), w2 = __expf(e2), w3 = __expf(e3);
            *(float4*)ew_sh[w][l] = make_float4(w0, w1, w2, w3);
            ds0 += w0;
            ds1 += w1;
            ds2 += w2;
            ds3 += w3;
        }
        int j = 0;
        for (; j + 7 < cnt; j += 8) {
            int4 oa = *(const int4*)&sidx_sh[w][j];
            int4 ob = *(const int4*)&sidx_sh[w][j + 4];
            float w0 = ew_sh[w][j + 0][hd], w1 = ew_sh[w][j + 1][hd];
            float w2 = ew_sh[w][j + 2][hd], w3 = ew_sh[w][j + 3][hd];
            float w4 = ew_sh[w][j + 4][hd], w5 = ew_sh[w][j + 5][hd];
            float w6 = ew_sh[w][j + 6][hd], w7 = ew_sh[w][j + 7][hd];
            if (FULL || l < ACT) {
                int2 p0 = *(const int2*)(hbl + oa.x);
                int2 p1 = *(const int2*)(hbl + oa.y);
                int2 p2 = *(const int2*)(hbl + oa.z);
                int2 p3 = *(const int2*)(hbl + oa.w);
                int2 p4 = *(const int2*)(hbl + ob.x);
                int2 p5 = *(const int2*)(hbl + ob.y);
                int2 p6 = *(const int2*)(hbl + ob.z);
                int2 p7 = *(const int2*)(hbl + ob.w);
                FMIX_LO(a0, p0.x, w0); FMIX_HI(a1, p0.x, w0);
                FMIX_LO(a2, p0.y, w0); FMIX_HI(a3, p0.y, w0);
                FMIX_LO(a0, p1.x, w1); FMIX_HI(a1, p1.x, w1);
                FMIX_LO(a2, p1.y, w1); FMIX_HI(a3, p1.y, w1);
                FMIX_LO(a0, p2.x, w2); FMIX_HI(a1, p2.x, w2);
                FMIX_LO(a2, p2.y, w2); FMIX_HI(a3, p2.y, w2);
                FMIX_LO(a0, p3.x, w3); FMIX_HI(a1, p3.x, w3);
                FMIX_LO(a2, p3.y, w3); FMIX_HI(a3, p3.y, w3);
                FMIX_LO(a0, p4.x, w4); FMIX_HI(a1, p4.x, w4);
                FMIX_LO(a2, p4.y, w4); FMIX_HI(a3, p4.y, w4);
                FMIX_LO(a0, p5.x, w5); FMIX_HI(a1, p5.x, w5);
                FMIX_LO(a2, p5.y, w5); FMIX_HI(a3, p5.y, w5);
                FMIX_LO(a0, p6.x, w6); FMIX_HI(a1, p6.x, w6);
                FMIX_LO(a2, p6.y, w6); FMIX_HI(a3, p6.y, w6);
                FMIX_LO(a0, p7.x, w7); FMIX_HI(a1, p7.x, w7);
                FMIX_LO(a2, p7.y, w7); FMIX_HI(a3, p7.y, w7);
            }
        }
        for (; j + 3 < cnt; j += 4) {
            int4 o4 = *(const int4*)&sidx_sh[w][j];
            float w0 = ew_sh[w][j + 0][hd], w1 = ew_sh[w][j + 1][hd];
            float w2 = ew_sh[w][j + 2][hd], w3 = ew_sh[w][j + 3][hd];
            if (FULL || l < ACT) {
                int2 p0 = *(const int2*)(hbl + o4.x);
                int2 p1 = *(const int2*)(hbl + o4.y);
                int2 p2 = *(const int2*)(hbl + o4.z);
                int2 p3 = *(const int2*)(hbl + o4.w);
                FMIX_LO(a0, p0.x, w0); FMIX_HI(a1, p0.x, w0);
                FMIX_LO(a2, p0.y, w0); FMIX_HI(a3, p0.y, w0);
                FMIX_LO(a0, p1.x, w1); FMIX_HI(a1, p1.x, w1);
                FMIX_LO(a2, p1.y, w1); FMIX_HI(a3, p1.y, w1);
                FMIX_LO(a0, p2.x, w2); FMIX_HI(a1, p2.x, w2);
                FMIX_LO(a2, p2.y, w2); FMIX_HI(a3, p2.y, w2);
                FMIX_LO(a0, p3.x, w3); FMIX_HI(a1, p3.x, w3);
                FMIX_LO(a2, p3.y, w3); FMIX_HI(a3, p3.y, w3);
            }
        }
        for (; j < cnt; j++) {
            int off = sidx_sh[w][j];
            float w0 = ew_sh[w][j][hd];
            if (FULL || l < ACT) {
                int2 p0 = *(const int2*)(hbl + off);
                FMIX_LO(a0, p0.x, w0); FMIX_HI(a1, p0.x, w0);
                FMIX_LO(a2, p0.y, w0); FMIX_HI(a3, p0.y, w0);
            }
        }
    }

#pragma unroll
    for (int off = 1; off < 64; off <<= 1) {
        ds0 += __shfl_xor(ds0, off);
        ds1 += __shfl_xor(ds1, off);
        ds2 += __shfl_xor(ds2, off);
        ds3 += __shfl_xor(ds3, off);
    }

    if (FULL || l < ACT) {
        float dsel = hd == 0 ? ds0 : hd == 1 ? ds1 : hd == 2 ? ds2 : ds3;
        float inv = 1.0f / dsel;
        float4 bv = ((const float4*)bias)[l];
        float r0 = a0 * inv + bv.x;
        float r1 = a1 * inv + bv.y;
        float r2 = a2 * inv + bv.z;
        float r3 = a3 * inv + bv.w;
        if (RELU) {
            r0 = fmaxf(r0, 0.f);
            r1 = fmaxf(r1, 0.f);
            r2 = fmaxf(r2, 0.f);
            r3 = fmaxf(r3, 0.f);
        }
        OutT* op = out + (long)node * HC + 4 * l;
        if (sizeof(OutT) == 2) {
            h4v hv;
            hv[0] = (_Float16)r0;
            hv[1] = (_Float16)r1;
            hv[2] = (_Float16)r2;
            hv[3] = (_Float16)r3;
            *(h4v*)op = hv;
        } else {
            *(float4*)op = make_float4(r0, r1, r2, r3);
        }
    }
}

// ---------------- launch ----------------
extern "C" void kernel_launch(void* const* d_in, const int* in_sizes, int n_in, void* d_out,
                              int out_size, void* d_ws, size_t ws_size, hipStream_t stream) {
    const float* x = (const float*)d_in[0];
    const void* ei = d_in[1];
    const float* W1 = (const float*)d_in[2];
    const float* attS1 = (const float*)d_in[3];
    const float* attD1 = (const float*)d_in[4];
    const float* b1 = (const float*)d_in[5];
    const float* W2 = (const float*)d_in[6];
    const float* attS2 = (const float*)d_in[7];
    const float* attD2 = (const float*)d_in[8];
    const float* b2 = (const float*)d_in[9];
    float* out = (float*)d_out;

    int N = in_sizes[0] / F_IN;  // 50000
    int E = in_sizes[1] / 2;     // 800000
    int nb = (N + 255) / 256;    // 196
    int nw = (N + 3) / 4;        // wave-per-node aggregate grid
    int nblk1 = (E + EB - 1) / EB;   // 391 level-1 edge blocks
    int nbuck = (N + NPB - 1) / NPB; // 196 node buckets (== nb)

    _Float16* xs_h = (_Float16*)d_ws;             // N*128
    _Float16* o1h = xs_h + (size_t)N * F_IN;      // N*256 (CSR-build scratch overlays early)
    _Float16* hb2 = o1h + (size_t)N * HC1;        // N*160
    _Float16* B1x = hb2 + (size_t)N * HC2;        // 272*128
    _Float16* B2x = B1x + (HC1 + 16) * F_IN;      // 176*256
    float* as1 = (float*)(B2x + (HC2 + 16) * HC1);
    float* ad1 = as1 + (size_t)N * NHEAD;
    float* as2 = ad1 + (size_t)N * NHEAD;
    float* ad2 = as2 + (size_t)N * NHEAD;
    float* stats = ad2 + (size_t)N * NHEAD;       // 256 (zeroed in detect_kernel)
    int* offsets = (int*)(stats + 256);           // N+1 (pad 4)
    int* csr = offsets + (N + 4);                 // E+N
    int* blocksum = csr + (E + N);                // 256
    int* mode = blocksum + 256;                   // 1
    // CSR-build scratch in o1h slot (dead before aggregate_x4g writes o1h): ~6.8MB < 25.6MB
    int* bucketEdges = (int*)o1h;                         // nbuck*BCAP (196*8192)
    int* hist = bucketEdges + (size_t)nbuck * BCAP;       // nbuck*nblk1 (bucket-major)
    int* colBaseT = hist + (size_t)nbuck * nblk1;         // nblk1*nbuck (block-major)
    int* bucketTotal = colBaseT + (size_t)nblk1 * nbuck;  // nbuck

    constexpr int TCV = (HC1 + 16) * F_IN + (HC2 + 16) * HC1;
    int nbConv = (TCV + 255) / 256;                      // 143
    int total4 = N * F_IN / 4;
    int nbStd = (total4 + 255) / 256;                    // 6250
    int nbG1 = (N + 63) / 64;                            // 782

    // 1. detect edge dtype + zero stats
    detect_kernel<<<1, 256, 0, stream>>>((const unsigned int*)ei, mode, stats);
    // 2. fused: bucket-hist | colstats | convert_w  (no far atomics)
    fused_pre_kernel<<<nblk1 + nb + nbConv, 256, 0, stream>>>(
        ei, mode, E, nbuck, nblk1, hist, x, stats, N, W1, attS1, attD1, B1x, W2, attS2, attD2,
        B2x, nb);
    // 3. fused: standardize | bucket col-scan
    fused_mid_kernel<<<nbStd + nbuck, 256, 0, stream>>>(x, stats, xs_h, total4,
                                                        1.0f / (float)N, 1.0f / (float)(N - 1),
                                                        hist, colBaseT, bucketTotal, nbuck,
                                                        nblk1, nbStd);
    // 4. level-1 scatter into bucket regions
    scatter1_kernel<<<nblk1, 256, 0, stream>>>(ei, mode, E, nbuck, colBaseT, bucketEdges);
    // 5. fused: per-bucket node counts + block-local scan
    bucket_count_scan_kernel<<<nbuck, 256, 0, stream>>>(bucketEdges, bucketTotal, offsets,
                                                        blocksum, N);
    // 6. scan_add (nb == nbuck == 196)
    scan_add_kernel<<<nb, 256, 0, stream>>>(blocksum, offsets, N, nb);
    // 7. fused: csr scatter | att1
    fused_csr_att1_kernel<<<nbuck + nbG1, 256, 0, stream>>>(bucketEdges, bucketTotal, offsets,
                                                            csr, N, nbuck, xs_h, B1x, as1, ad1);
    // 8. fused: per-head aggregate in xs-space + per-node GEMM -> o1 (kills aggx traffic)
    aggregate_x4g_kernel<<<nw, 256, 0, stream>>>(xs_h, as1, ad1, offsets, csr, B1x, b1, o1h,
                                                 N);
    // 9. gemm2(+att2)  (LDS-staged B)
    gemm2_kernel<<<nbG1 * 2, 256, 0, stream>>>(o1h, B2x, hb2, as2, ad2, N);
    // 10. aggregate layer 2 (R8 compiler-scheduled form)
    aggregate_kernel<HC2, false, float>
        <<<nw, 256, 0, stream>>>(hb2, as2, ad2, offsets, csr, b2, out, N);
}

// Round 13
// 291.885 us; speedup vs baseline: 1.3003x; 1.3003x over previous
//
#include <hip/hip_runtime.h>
#include <math.h>

#define NEG_SLOPE 0.2f

constexpr int F_IN  = 128;
constexpr int HC1   = 256;  // H*HID
constexpr int HC2   = 160;  // H*CLS
constexpr int NHEAD = 4;
constexpr int EB    = 2048; // edges per level-1 block
constexpr int NPB   = 256;  // nodes per bucket (== scan block size -> count+scan fuse)
constexpr int BCAP  = 8192; // bucket capacity (avg 4083 @ E=800k; +64 sigma safe)

typedef _Float16 h8v __attribute__((ext_vector_type(8)));
typedef _Float16 h4v __attribute__((ext_vector_type(4)));
typedef _Float16 h2v __attribute__((ext_vector_type(2)));
typedef float f4v __attribute__((ext_vector_type(4)));

// f32 += f16(lo/hi of packed) * f32 — single VOP3P instruction
#define FMIX_LO(acc, pk, wt) \
    asm("v_fma_mix_f32 %0, %1, %2, %0 op_sel:[0,0,0] op_sel_hi:[1,0,0]" \
        : "+v"(acc) : "v"(pk), "v"(wt))
#define FMIX_HI(acc, pk, wt) \
    asm("v_fma_mix_f32 %0, %1, %2, %0 op_sel:[1,0,0] op_sel_hi:[1,0,0]" \
        : "+v"(acc) : "v"(pk), "v"(wt))

__device__ __forceinline__ int edge_val(const void* p, int m64, long long i) {
    if (m64) return (int)((const long long*)p)[i];
    return ((const int*)p)[i];
}

// ---------------- dispatch 1: edge dtype detect (+ zero stats) ----------------
__global__ void detect_kernel(const unsigned int* __restrict__ ei_words, int* __restrict__ mode,
                              float* __restrict__ stats) {
    stats[threadIdx.x] = 0.f;  // 256 threads zero 256 floats (sum|sumsq)
    __shared__ unsigned int red[256];
    unsigned int v = 0;
    for (int i = 1 + 2 * (int)threadIdx.x; i < 4096; i += 512) v |= ei_words[i];
    red[threadIdx.x] = v;
    __syncthreads();
    for (int off = 128; off > 0; off >>= 1) {
        if (threadIdx.x < off) red[threadIdx.x] |= red[threadIdx.x + off];
        __syncthreads();
    }
    if (threadIdx.x == 0) *mode = (red[0] == 0u) ? 1 : 0;
}

// ---------------- dispatch 2 (fused): bucket-hist | colstats | convert_w ----------------
__global__ __launch_bounds__(256) void fused_pre_kernel(
    const void* __restrict__ ei, const int* __restrict__ mode, int E, int nbuck, int nblk1,
    int* __restrict__ hist, const float* __restrict__ x, float* __restrict__ stats, int N,
    const float* __restrict__ W1, const float* __restrict__ aS1, const float* __restrict__ aD1,
    _Float16* __restrict__ B1x, const float* __restrict__ W2, const float* __restrict__ aS2,
    const float* __restrict__ aD2, _Float16* __restrict__ B2x, int nbStats) {
    int b = blockIdx.x;
    if (b < nblk1) {
        // ---- level-1 histogram (bucket = dst >> 8) ----
        __shared__ int lh[256];
        for (int i = threadIdx.x; i < nbuck; i += 256) lh[i] = 0;
        __syncthreads();
        int m = *mode;
        long long e0 = (long long)b * EB;
#pragma unroll
        for (int k = 0; k < EB / 256; k++) {
            long long e = e0 + (int)threadIdx.x + k * 256;
            if (e < E) {
                int d = edge_val(ei, m, (long long)E + e);
                atomicAdd(&lh[d >> 8], 1);
            }
        }
        __syncthreads();
        for (int i = threadIdx.x; i < nbuck; i += 256) hist[(size_t)i * nblk1 + b] = lh[i];
    } else if (b < nblk1 + nbStats) {
        // ---- colstats: float4 loads, 32 iters/thread, LDS-reduce 8 row groups ----
        int t = (int)threadIdx.x;
        int c = t & 31;   // handles cols 4c..4c+3
        int g = t >> 5;   // row subgroup 0..7
        int r0 = (b - nblk1) * 256;
        int rend = min(r0 + 256, N);
        f4v s = {0.f, 0.f, 0.f, 0.f}, q = {0.f, 0.f, 0.f, 0.f};
        for (int r = r0 + g; r < rend; r += 8) {
            f4v v = *(const f4v*)&x[(long)r * F_IN + 4 * c];
            s += v;
            q += v * v;
        }
        __shared__ f4v sh4[256];
        sh4[t] = s;
        __syncthreads();
        if (t < 32) {
            f4v a = sh4[t];
            for (int g2 = 1; g2 < 8; g2++) a += sh4[g2 * 32 + t];
            atomicAdd(&stats[4 * t + 0], a[0]);
            atomicAdd(&stats[4 * t + 1], a[1]);
            atomicAdd(&stats[4 * t + 2], a[2]);
            atomicAdd(&stats[4 * t + 3], a[3]);
        }
        __syncthreads();
        sh4[t] = q;
        __syncthreads();
        if (t < 32) {
            f4v a = sh4[t];
            for (int g2 = 1; g2 < 8; g2++) a += sh4[g2 * 32 + t];
            atomicAdd(&stats[128 + 4 * t + 0], a[0]);
            atomicAdd(&stats[128 + 4 * t + 1], a[1]);
            atomicAdd(&stats[128 + 4 * t + 2], a[2]);
            atomicAdd(&stats[128 + 4 * t + 3], a[3]);
        }
    } else {
        // ---- convert weights -> fp16 transposed + att columns ----
        constexpr int T1 = (HC1 + 16) * F_IN;
        constexpr int T2 = (HC2 + 16) * HC1;
        int idx = (b - nblk1 - nbStats) * 256 + (int)threadIdx.x;
        if (idx < T1) {
            int n = idx / F_IN, k = idx - n * F_IN;
            float v = 0.f;
            if (n < HC1) {
                v = W1[k * HC1 + n];
            } else {
                int n2 = n - HC1;
                if (n2 < 8) {
                    int hd = n2 & 3;
                    const float* a = (n2 < 4) ? aS1 : aD1;
                    for (int c = 0; c < 64; c++) v += W1[k * HC1 + hd * 64 + c] * a[hd * 64 + c];
                }
            }
            B1x[n * F_IN + k] = (_Float16)v;
        } else if (idx < T1 + T2) {
            int i2 = idx - T1;
            int n = i2 / HC1, k = i2 - n * HC1;
            float v = 0.f;
            if (n < HC2) {
                v = W2[k * HC2 + n];
            } else {
                int n2 = n - HC2;
                if (n2 < 8) {
                    int hd = n2 & 3;
                    const float* a = (n2 < 4) ? aS2 : aD2;
                    for (int c = 0; c < 40; c++) v += W2[k * HC2 + hd * 40 + c] * a[hd * 40 + c];
                }
            }
            B2x[n * HC1 + k] = (_Float16)v;
        }
    }
}

// ---------------- dispatch 3 (fused): standardize | bucket col-scan ----------------
__global__ __launch_bounds__(256) void fused_mid_kernel(
    const float* __restrict__ x, const float* __restrict__ stats, _Float16* __restrict__ xs,
    int total4, float invN, float invN1, const int* __restrict__ hist,
    int* __restrict__ colBaseT, int* __restrict__ bucketTotal, int nbuck, int nblk1,
    int nbStd) {
    int b = blockIdx.x;
    if (b < nbStd) {
        int i = b * 256 + (int)threadIdx.x;
        if (i >= total4) return;
        int c = (i * 4) & (F_IN - 1);
        float4 s4 = *(const float4*)&stats[c];
        float4 q4 = *(const float4*)&stats[128 + c];
        float4 v = ((const float4*)x)[i];
        h4v o;
        o[0] = (_Float16)((v.x - s4.x * invN) / sqrtf((q4.x - s4.x * s4.x * invN) * invN1));
        o[1] = (_Float16)((v.y - s4.y * invN) / sqrtf((q4.y - s4.y * s4.y * invN) * invN1));
        o[2] = (_Float16)((v.z - s4.z * invN) / sqrtf((q4.z - s4.z * s4.z * invN) * invN1));
        o[3] = (_Float16)((v.w - s4.w * invN) / sqrtf((q4.w - s4.w * s4.w * invN) * invN1));
        ((h4v*)xs)[i] = o;
    } else {
        // col-scan: exclusive prefix over blocks of hist[bb][*]; write transposed
        int bb = b - nbStd;
        int t = (int)threadIdx.x;
        __shared__ int sh[512];
        __shared__ int wsum[4];
        for (int i = t; i < nblk1; i += 256) sh[i] = hist[(size_t)bb * nblk1 + i];
        __syncthreads();
        int carry = 0;
        for (int base = 0; base < nblk1; base += 256) {
            int idx = base + t;
            int v = (idx < nblk1) ? sh[idx] : 0;
            int lane = t & 63, w = t >> 6;
            int xv = v;
#pragma unroll
            for (int d = 1; d < 64; d <<= 1) {
                int y = __shfl_up(xv, d);
                if (lane >= d) xv += y;
            }
            if (lane == 63) wsum[w] = xv;
            __syncthreads();
            int wb = 0;
            for (int k = 0; k < w; k++) wb += wsum[k];
            int excl = xv - v + wb + carry;
            if (idx < nblk1) colBaseT[(size_t)idx * nbuck + bb] = excl;
            carry += wsum[0] + wsum[1] + wsum[2] + wsum[3];
            __syncthreads();
        }
        if (t == 0) bucketTotal[bb] = carry;
    }
}

// ---------------- dispatch 4: level-1 scatter into bucket regions ----------------
__global__ __launch_bounds__(256) void scatter1_kernel(const void* __restrict__ ei,
                                                       const int* __restrict__ mode, int E,
                                                       int nbuck,
                                                       const int* __restrict__ colBaseT,
                                                       int* __restrict__ bucketEdges) {
    __shared__ int cur[256];
    int b = blockIdx.x;
    for (int i = threadIdx.x; i < nbuck; i += 256)
        cur[i] = colBaseT[(size_t)b * nbuck + i];
    __syncthreads();
    int m = *mode;
    long long e0 = (long long)b * EB;
#pragma unroll
    for (int k = 0; k < EB / 256; k++) {
        long long e = e0 + (int)threadIdx.x + k * 256;
        if (e < E) {
            int s = edge_val(ei, m, e);
            int d = edge_val(ei, m, (long long)E + e);
            int bk = d >> 8;
            int r = atomicAdd(&cur[bk], 1);  // LDS returning atomic (fast)
            bucketEdges[(size_t)bk * BCAP + r] = s | ((d & (NPB - 1)) << 16);
        }
    }
}

// ---------------- dispatch 5 (fused): per-bucket node counts + local scan ------------
__global__ __launch_bounds__(256) void bucket_count_scan_kernel(
    const int* __restrict__ bucketEdges, const int* __restrict__ bucketTotal,
    int* __restrict__ offsets, int* __restrict__ blocksum, int N) {
    __shared__ int c[NPB];
    int b = blockIdx.x, t = threadIdx.x;
    c[t] = 0;
    __syncthreads();
    int cnt = bucketTotal[b];
    const int* be = bucketEdges + (size_t)b * BCAP;
    for (int i = t; i < cnt; i += 256) atomicAdd(&c[(be[i] >> 16) & (NPB - 1)], 1);
    __syncthreads();
    int node = b * NPB + t;
    int v = (node < N) ? c[t] + 1 : 0;  // +1 self loop
    int lane = t & 63, w = t >> 6;
    int xv = v;
#pragma unroll
    for (int d = 1; d < 64; d <<= 1) {
        int y = __shfl_up(xv, d);
        if (lane >= d) xv += y;
    }
    __shared__ int wsum[4];
    if (lane == 63) wsum[w] = xv;
    __syncthreads();
    int base = 0;
    for (int k = 0; k < w; k++) base += wsum[k];
    int incl = xv + base;
    if (node < N) offsets[node + 1] = incl;
    if (t == 255) blocksum[b] = incl;
}

// ---------------- dispatch 6: scan_add ----------------
__global__ void scan_add_kernel(const int* __restrict__ blocksum, int* __restrict__ offsets, int N,
                                int nb) {
    int t = threadIdx.x;
    int v = (t < nb) ? blocksum[t] : 0;
    int lane = t & 63, w = t >> 6;
    int x = v;
#pragma unroll
    for (int d = 1; d < 64; d <<= 1) {
        int y = __shfl_up(x, d);
        if (lane >= d) x += y;
    }
    __shared__ int wsum[4];
    __shared__ int excl[256];
    if (lane == 63) wsum[w] = x;
    __syncthreads();
    int base = 0;
    for (int k = 0; k < w; k++) base += wsum[k];
    excl[t] = x + base - v;
    __syncthreads();
    int myb = excl[blockIdx.x];
    int i = blockIdx.x * 256 + t;
    if (i < N) offsets[i + 1] += myb;
    if (i == 0) offsets[0] = 0;
}

// ---------------- att1 mini-GEMM: as1/ad1 = xs @ (W1·att) (8 cols) ----------------
__device__ __forceinline__ void att1_body(int blk, const _Float16* __restrict__ A,
                                          const _Float16* __restrict__ Batt,
                                          float* __restrict__ as_, float* __restrict__ ad_,
                                          int M) {
    constexpr int KT = F_IN / 32;  // 4
    int w = threadIdx.x >> 6;
    int l = threadIdx.x & 63;
    int quad = l >> 4, lan = l & 15;
    int row = blk * 64 + w * 16 + lan;
    int arow = min(row, M - 1);
    const _Float16* Aptr = A + (long)arow * F_IN + quad * 8;
    h8v afr[KT], bfr[KT];
#pragma unroll
    for (int k0 = 0; k0 < KT; k0++) afr[k0] = *(const h8v*)(Aptr + k0 * 32);
#pragma unroll
    for (int k0 = 0; k0 < KT; k0++)
        bfr[k0] = *(const h8v*)(Batt + (long)lan * F_IN + k0 * 32 + quad * 8);
    f4v acc = {0.f, 0.f, 0.f, 0.f};
#pragma unroll
    for (int k0 = 0; k0 < KT; k0++)
        acc = __builtin_amdgcn_mfma_f32_16x16x32_f16(afr[k0], bfr[k0], acc, 0, 0, 0);
    int orow = blk * 64 + w * 16 + quad * 4;
#pragma unroll
    for (int r = 0; r < 4; r++) {
        int gr = orow + r;
        if (gr < M) {
            float av = acc[r];
            if (lan < 4)
                as_[gr * 4 + lan] = av;
            else if (lan < 8)
                ad_[gr * 4 + lan - 4] = av;
        }
    }
}

// ---------------- dispatch 7 (fused): csr-scatter | att1 ----------------
__global__ __launch_bounds__(256) void fused_csr_att1_kernel(
    const int* __restrict__ bucketEdges, const int* __restrict__ bucketTotal,
    const int* __restrict__ offsets, int* __restrict__ csr, int N, int nbuck,
    const _Float16* __restrict__ xs, const _Float16* __restrict__ B1x,
    float* __restrict__ as_, float* __restrict__ ad_) {
    int b = blockIdx.x;
    if (b < nbuck) {
        __shared__ int cur[NPB];
        int t = threadIdx.x;
        int node = b * NPB + t;
        if (node < N) {
            int off = offsets[node];
            csr[off] = node;  // self loop at slot 0
            cur[t] = off + 1;
        }
        __syncthreads();
        int cnt = bucketTotal[b];
        const int* be = bucketEdges + (size_t)b * BCAP;
        for (int i = t; i < cnt; i += 256) {
            int v = be[i];
            int pos = atomicAdd(&cur[(v >> 16) & (NPB - 1)], 1);  // LDS returning atomic
            csr[pos] = v & 0xFFFF;
        }
    } else {
        att1_body(b - nbuck, xs, B1x + (size_t)HC1 * F_IN, as_, ad_, N);
    }
}

// ---------------- dispatch 8: per-head layer-1 aggregate in xs-space (R8 form) --------
__global__ __launch_bounds__(256, 4) void aggregate_x4_kernel(
    const _Float16* __restrict__ xs, const float* __restrict__ a_src,
    const float* __restrict__ a_dst, const int* __restrict__ offsets,
    const int* __restrict__ csr_src, _Float16* __restrict__ aggx_lo,
    _Float16* __restrict__ aggx_hi, int Ntot) {
    int w = threadIdx.x >> 6, l = threadIdx.x & 63;
    int node = blockIdx.x * 4 + w;
    if (node >= Ntot) return;  // wave-uniform exit

    __shared__ __align__(16) int sidx_sh[4][64];     // byte offsets into xs (row = 256B)
    __shared__ __align__(16) float ew_sh[4][64][4];  // per-edge per-head exp weights

    int start = offsets[node], deg = offsets[node + 1] - start;
    float4 adv = ((const float4*)a_dst)[node];
    const char* hbl = (const char*)xs + 4 * l;  // this lane's 2-channel slice

    float ds0 = 0.f, ds1 = 0.f, ds2 = 0.f, ds3 = 0.f;
    float a00 = 0.f, a01 = 0.f, a10 = 0.f, a11 = 0.f;
    float a20 = 0.f, a21 = 0.f, a30 = 0.f, a31 = 0.f;

#define X4_EDGE(p, wv)                                   \
    do {                                                 \
        FMIX_LO(a00, p, wv.x); FMIX_HI(a01, p, wv.x);    \
        FMIX_LO(a10, p, wv.y); FMIX_HI(a11, p, wv.y);    \
        FMIX_LO(a20, p, wv.z); FMIX_HI(a21, p, wv.z);    \
        FMIX_LO(a30, p, wv.w); FMIX_HI(a31, p, wv.w);    \
    } while (0)

    for (int base = 0; base < deg; base += 64) {
        int cnt = min(64, deg - base);
        if (l < cnt) {
            int s = csr_src[start + base + l];
            sidx_sh[w][l] = s * (F_IN * 2);
            float4 av = ((const float4*)a_src)[s];
            float e0 = av.x + adv.x, e1 = av.y + adv.y, e2 = av.z + adv.z, e3 = av.w + adv.w;
            e0 = fmaxf(e0, NEG_SLOPE * e0);
            e1 = fmaxf(e1, NEG_SLOPE * e1);
            e2 = fmaxf(e2, NEG_SLOPE * e2);
            e3 = fmaxf(e3, NEG_SLOPE * e3);
            float w0 = __expf(e0), w1 = __expf(e1), w2 = __expf(e2), w3 = __expf(e3);
            *(float4*)ew_sh[w][l] = make_float4(w0, w1, w2, w3);
            ds0 += w0;
            ds1 += w1;
            ds2 += w2;
            ds3 += w3;
        }
        int j = 0;
        for (; j + 3 < cnt; j += 4) {
            int4 o4 = *(const int4*)&sidx_sh[w][j];
            float4 wa = *(const float4*)ew_sh[w][j + 0];
            float4 wb = *(const float4*)ew_sh[w][j + 1];
            float4 wc = *(const float4*)ew_sh[w][j + 2];
            float4 wd = *(const float4*)ew_sh[w][j + 3];
            int p0 = *(const int*)(hbl + o4.x);
            int p1 = *(const int*)(hbl + o4.y);
            int p2 = *(const int*)(hbl + o4.z);
            int p3 = *(const int*)(hbl + o4.w);
            X4_EDGE(p0, wa);
            X4_EDGE(p1, wb);
            X4_EDGE(p2, wc);
            X4_EDGE(p3, wd);
        }
        for (; j < cnt; j++) {
            int off = sidx_sh[w][j];
            float4 wa = *(const float4*)ew_sh[w][j];
            int p0 = *(const int*)(hbl + off);
            X4_EDGE(p0, wa);
        }
    }
#undef X4_EDGE

#pragma unroll
    for (int off = 1; off < 64; off <<= 1) {
        ds0 += __shfl_xor(ds0, off);
        ds1 += __shfl_xor(ds1, off);
        ds2 += __shfl_xor(ds2, off);
        ds3 += __shfl_xor(ds3, off);
    }

    float i0 = 1.0f / ds0, i1 = 1.0f / ds1, i2 = 1.0f / ds2, i3 = 1.0f / ds3;
    h2v hv;
    hv[0] = (_Float16)(a00 * i0);
    hv[1] = (_Float16)(a01 * i0);
    *(h2v*)(aggx_lo + (size_t)node * F_IN + 2 * l) = hv;
    hv[0] = (_Float16)(a10 * i1);
    hv[1] = (_Float16)(a11 * i1);
    *(h2v*)(aggx_lo + ((size_t)Ntot + node) * F_IN + 2 * l) = hv;
    hv[0] = (_Float16)(a20 * i2);
    hv[1] = (_Float16)(a21 * i2);
    *(h2v*)(aggx_hi + (size_t)node * F_IN + 2 * l) = hv;
    hv[0] = (_Float16)(a30 * i3);
    hv[1] = (_Float16)(a31 * i3);
    *(h2v*)(aggx_hi + ((size_t)Ntot + node) * F_IN + 2 * l) = hv;
}

// ---------------- dispatch 9: gemm1b with fragment-linear LDS-staged B ----------------
template <int CT0, int CT1>
__device__ __forceinline__ void gemm1b_lds_body(int blk, const _Float16* __restrict__ Ah,
                                                const _Float16* __restrict__ Btx,
                                                _Float16* Bs, const float* __restrict__ bias,
                                                _Float16* __restrict__ C_, int M) {
    constexpr int NC = CT1 - CT0;  // 8
    constexpr int KT = F_IN / 32;  // 4
    int t = threadIdx.x;
    int w = t >> 6, l = t & 63;
    int quad = l >> 4, lan = l & 15;
    int row = blk * 64 + w * 16 + lan;
    int arow = min(row, M - 1);
    const _Float16* A0 = Ah + (size_t)arow * F_IN + quad * 8;        // head CT0/4
    const _Float16* A1 = Ah + ((size_t)M + arow) * F_IN + quad * 8;  // head CT0/4+1
    h8v af0[KT], af1[KT];
#pragma unroll
    for (int k0 = 0; k0 < KT; k0++) af0[k0] = *(const h8v*)(A0 + k0 * 32);
#pragma unroll
    for (int k0 = 0; k0 < KT; k0++) af1[k0] = *(const h8v*)(A1 + k0 * 32);
#pragma unroll
    for (int jj = 0; jj < NC * KT * 64 / 256; jj++) {  // 8 iters
        int j = jj * 256 + t;
        int cik = j >> 6;
        int k0_ = cik % KT, ci_ = cik / KT;
        int jl = j & 63;
        const _Float16* src =
            Btx + (long)((CT0 + ci_) * 16 + (jl & 15)) * F_IN + k0_ * 32 + (jl >> 4) * 8;
        *(h8v*)(Bs + (size_t)j * 8) = *(const h8v*)src;
    }
    __syncthreads();
    f4v acc[NC] = {};
#pragma unroll
    for (int k0 = 0; k0 < KT; k0++)
#pragma unroll
        for (int ci = 0; ci < NC; ci++) {
            h8v bf = *(const h8v*)(Bs + ((size_t)(ci * KT + k0) * 64 + l) * 8);
            h8v af = (ci < 4) ? af0[k0] : af1[k0];
            acc[ci] = __builtin_amdgcn_mfma_f32_16x16x32_f16(af, bf, acc[ci], 0, 0, 0);
        }
    int orow = blk * 64 + w * 16 + quad * 4;
#pragma unroll
    for (int r = 0; r < 4; r++) {
        int gr = orow + r;
        if (gr < M) {
            _Float16* out = C_ + (long)gr * HC1 + lan;
#pragma unroll
            for (int ci = 0; ci < NC; ci++) {
                int ct = CT0 + ci;
                float v = acc[ci][r] + bias[ct * 16 + lan];
                out[ct * 16] = (_Float16)fmaxf(v, 0.f);
            }
        }
    }
}

__global__ __launch_bounds__(256, 3) void gemm1b_kernel(const _Float16* __restrict__ Alo,
                                                        const _Float16* __restrict__ Ahi,
                                                        const _Float16* __restrict__ Btx,
                                                        const float* __restrict__ bias,
                                                        _Float16* __restrict__ C_, int M) {
    __shared__ __align__(16) _Float16 Bs[8 * 4 * 64 * 8];  // 32KB
    int blk = blockIdx.x >> 1;
    if (blockIdx.x & 1)
        gemm1b_lds_body<8, 16>(blk, Ahi, Btx, Bs, bias, C_, M);  // heads 2,3
    else
        gemm1b_lds_body<0, 8>(blk, Alo, Btx, Bs, bias, C_, M);   // heads 0,1
}

// ---------------- dispatch 10: gemm2(+att2) with fragment-linear LDS-staged B ----------
template <int CT0, int CT1>
__device__ __forceinline__ void gemm2_lds_body(int blk, const _Float16* __restrict__ A,
                                               const _Float16* __restrict__ Btx,
                                               _Float16* Bs, _Float16* __restrict__ C_,
                                               float* __restrict__ as_, float* __restrict__ ad_,
                                               int M) {
    constexpr int NT = HC2 / 16;   // 10
    constexpr int NC = CT1 - CT0;  // 5 or 6
    constexpr int KT = HC1 / 32;   // 8
    int t = threadIdx.x;
    int w = t >> 6, l = t & 63;
    int quad = l >> 4, lan = l & 15;
    int row = blk * 64 + w * 16 + lan;
    int arow = min(row, M - 1);
    const _Float16* Aptr = A + (long)arow * HC1 + quad * 8;
    h8v afr[KT];
#pragma unroll
    for (int k0 = 0; k0 < KT; k0++) afr[k0] = *(const h8v*)(Aptr + k0 * 32);
#pragma unroll
    for (int jj = 0; jj < NC * KT * 64 / 256; jj++) {  // 10 or 12 iters
        int j = jj * 256 + t;
        int cik = j >> 6;
        int k0_ = cik % KT, ci_ = cik / KT;
        int jl = j & 63;
        const _Float16* src =
            Btx + (long)((CT0 + ci_) * 16 + (jl & 15)) * HC1 + k0_ * 32 + (jl >> 4) * 8;
        *(h8v*)(Bs + (size_t)j * 8) = *(const h8v*)src;
    }
    __syncthreads();
    f4v acc[NC] = {};
#pragma unroll
    for (int k0 = 0; k0 < KT; k0++)
#pragma unroll
        for (int ci = 0; ci < NC; ci++) {
            h8v bf = *(const h8v*)(Bs + ((size_t)(ci * KT + k0) * 64 + l) * 8);
            acc[ci] = __builtin_amdgcn_mfma_f32_16x16x32_f16(afr[k0], bf, acc[ci], 0, 0, 0);
        }
    int orow = blk * 64 + w * 16 + quad * 4;
#pragma unroll
    for (int r = 0; r < 4; r++) {
        int gr = orow + r;
        if (gr < M) {
            _Float16* out = C_ + (long)gr * HC2 + lan;
#pragma unroll
            for (int ci = 0; ci < NC; ci++) {
                int ct = CT0 + ci;
                if (ct < NT) out[ct * 16] = (_Float16)acc[ci][r];
            }
            if (CT1 == NT + 1) {
                float av = acc[NC - 1][r];
                if (lan < 4)
                    as_[gr * 4 + lan] = av;
                else if (lan < 8)
                    ad_[gr * 4 + lan - 4] = av;
            }
        }
    }
}

__global__ __launch_bounds__(256, 3) void gemm2_kernel(const _Float16* __restrict__ A,
                                                       const _Float16* __restrict__ B2x,
                                                       _Float16* __restrict__ C_,
                                                       float* __restrict__ as_,
                                                       float* __restrict__ ad_, int M) {
    __shared__ __align__(16) _Float16 Bs[6 * 8 * 64 * 8];  // 48KB (odd half size)
    int blk = blockIdx.x >> 1;
    if (blockIdx.x & 1)
        gemm2_lds_body<5, 11>(blk, A, B2x, Bs, C_, as_, ad_, M);  // tiles 5-9 + att
    else
        gemm2_lds_body<0, 5>(blk, A, B2x, Bs, C_, as_, ad_, M);   // tiles 0-4
}

// ---------------- dispatch 11: layer-2 aggregate (R8 compiler-scheduled form) ----------
template <int HC, bool RELU, typename OutT>
__global__ __launch_bounds__(256, 4) void aggregate_kernel(
    const _Float16* __restrict__ hb, const float* __restrict__ a_src,
    const float* __restrict__ a_dst, const int* __restrict__ offsets,
    const int* __restrict__ csr_src, const float* __restrict__ bias, OutT* __restrict__ out,
    int Ntot) {
    constexpr int ACT = HC / 4;       // active gather lanes (64 or 40)
    constexpr int CHPH = HC / NHEAD;  // channels per head
    constexpr bool FULL = (ACT == 64);
    int w = threadIdx.x >> 6, l = threadIdx.x & 63;
    int node = blockIdx.x * 4 + w;
    if (node >= Ntot) return;  // wave-uniform exit

    __shared__ __align__(16) int sidx_sh[4][64];     // byte offsets into hb
    __shared__ __align__(16) float ew_sh[4][64][4];  // per-edge per-head exp weights

    int start = offsets[node], end = offsets[node + 1];
    int deg = end - start;
    float4 adv = ((const float4*)a_dst)[node];
    const int hd = min((4 * l) / CHPH, 3);
    const char* hbl = (const char*)hb + 8 * l;  // this lane's 4-channel slice

    float ds0 = 0.f, ds1 = 0.f, ds2 = 0.f, ds3 = 0.f;
    float a0 = 0.f, a1 = 0.f, a2 = 0.f, a3 = 0.f;

    for (int base = 0; base < deg; base += 64) {
        int cnt = min(64, deg - base);
        if (l < cnt) {
            int s = csr_src[start + base + l];
            sidx_sh[w][l] = s * (HC * 2);
            float4 av = ((const float4*)a_src)[s];
            float e0 = av.x + adv.x, e1 = av.y + adv.y, e2 = av.z + adv.z, e3 = av.w + adv.w;
            e0 = fmaxf(e0, NEG_SLOPE * e0);
            e1 = fmaxf(e1, NEG_SLOPE * e1);
            e2 = fmaxf(e2, NEG_SLOPE * e2);
            e3 = fmaxf(e3, NEG_SLOPE * e3);
            float w0 = __expf(e0), w1 = __expf(e1), w2 = __expf(e2), w3 = __expf(e3);
            *(float4*)ew_sh[w][l] = make_float4(w0, w1, w2, w3);
            ds0 += w0;
            ds1 += w1;
            ds2 += w2;
            ds3 += w3;
        }
        int j = 0;
        for (; j + 7 < cnt; j += 8) {
            int4 oa = *(const int4*)&sidx_sh[w][j];
            int4 ob = *(const int4*)&sidx_sh[w][j + 4];
            float w0 = ew_sh[w][j + 0][hd], w1 = ew_sh[w][j + 1][hd];
            float w2 = ew_sh[w][j + 2][hd], w3 = ew_sh[w][j + 3][hd];
            float w4 = ew_sh[w][j + 4][hd], w5 = ew_sh[w][j + 5][hd];
            float w6 = ew_sh[w][j + 6][hd], w7 = ew_sh[w][j + 7][hd];
            if (FULL || l < ACT) {
                int2 p0 = *(const int2*)(hbl + oa.x);
                int2 p1 = *(const int2*)(hbl + oa.y);
                int2 p2 = *(const int2*)(hbl + oa.z);
                int2 p3 = *(const int2*)(hbl + oa.w);
                int2 p4 = *(const int2*)(hbl + ob.x);
                int2 p5 = *(const int2*)(hbl + ob.y);
                int2 p6 = *(const int2*)(hbl + ob.z);
                int2 p7 = *(const int2*)(hbl + ob.w);
                FMIX_LO(a0, p0.x, w0); FMIX_HI(a1, p0.x, w0);
                FMIX_LO(a2, p0.y, w0); FMIX_HI(a3, p0.y, w0);
                FMIX_LO(a0, p1.x, w1); FMIX_HI(a1, p1.x, w1);
                FMIX_LO(a2, p1.y, w1); FMIX_HI(a3, p1.y, w1);
                FMIX_LO(a0, p2.x, w2); FMIX_HI(a1, p2.x, w2);
                FMIX_LO(a2, p2.y, w2); FMIX_HI(a3, p2.y, w2);
                FMIX_LO(a0, p3.x, w3); FMIX_HI(a1, p3.x, w3);
                FMIX_LO(a2, p3.y, w3); FMIX_HI(a3, p3.y, w3);
                FMIX_LO(a0, p4.x, w4); FMIX_HI(a1, p4.x, w4);
                FMIX_LO(a2, p4.y, w4); FMIX_HI(a3, p4.y, w4);
                FMIX_LO(a0, p5.x, w5); FMIX_HI(a1, p5.x, w5);
                FMIX_LO(a2, p5.y, w5); FMIX_HI(a3, p5.y, w5);
                FMIX_LO(a0, p6.x, w6); FMIX_HI(a1, p6.x, w6);
                FMIX_LO(a2, p6.y, w6); FMIX_HI(a3, p6.y, w6);
                FMIX_LO(a0, p7.x, w7); FMIX_HI(a1, p7.x, w7);
                FMIX_LO(a2, p7.y, w7); FMIX_HI(a3, p7.y, w7);
            }
        }
        for (; j + 3 < cnt; j += 4) {
            int4 o4 = *(const int4*)&sidx_sh[w][j];
            float w0 = ew_sh[w][j + 0][hd], w1 = ew_sh[w][j + 1][hd];
            float w2 = ew_sh[w][j + 2][hd], w3 = ew_sh[w][j + 3][hd];
            if (FULL || l < ACT) {
                int2 p0 = *(const int2*)(hbl + o4.x);
                int2 p1 = *(const int2*)(hbl + o4.y);
                int2 p2 = *(const int2*)(hbl + o4.z);
                int2 p3 = *(const int2*)(hbl + o4.w);
                FMIX_LO(a0, p0.x, w0); FMIX_HI(a1, p0.x, w0);
                FMIX_LO(a2, p0.y, w0); FMIX_HI(a3, p0.y, w0);
                FMIX_LO(a0, p1.x, w1); FMIX_HI(a1, p1.x, w1);
                FMIX_LO(a2, p1.y, w1); FMIX_HI(a3, p1.y, w1);
                FMIX_LO(a0, p2.x, w2); FMIX_HI(a1, p2.x, w2);
                FMIX_LO(a2, p2.y, w2); FMIX_HI(a3, p2.y, w2);
                FMIX_LO(a0, p3.x, w3); FMIX_HI(a1, p3.x, w3);
                FMIX_LO(a2, p3.y, w3); FMIX_HI(a3, p3.y, w3);
            }
        }
        for (; j < cnt; j++) {
            int off = sidx_sh[w][j];
            float w0 = ew_sh[w][j][hd];
            if (FULL || l < ACT) {
                int2 p0 = *(const int2*)(hbl + off);
                FMIX_LO(a0, p0.x, w0); FMIX_HI(a1, p0.x, w0);
                FMIX_LO(a2, p0.y, w0); FMIX_HI(a3, p0.y, w0);
            }
        }
    }

#pragma unroll
    for (int off = 1; off < 64; off <<= 1) {
        ds0 += __shfl_xor(ds0, off);
        ds1 += __shfl_xor(ds1, off);
        ds2 += __shfl_xor(ds2, off);
        ds3 += __shfl_xor(ds3, off);
    }

    if (FULL || l < ACT) {
        float dsel = hd == 0 ? ds0 : hd == 1 ? ds1 : hd == 2 ? ds2 : ds3;
        float inv = 1.0f / dsel;
        float4 bv = ((const float4*)bias)[l];
        float r0 = a0 * inv + bv.x;
        float r1 = a1 * inv + bv.y;
        float r2 = a2 * inv + bv.z;
        float r3 = a3 * inv + bv.w;
        if (RELU) {
            r0 = fmaxf(r0, 0.f);
            r1 = fmaxf(r1, 0.f);
            r2 = fmaxf(r2, 0.f);
            r3 = fmaxf(r3, 0.f);
        }
        OutT* op = out + (long)node * HC + 4 * l;
        if (sizeof(OutT) == 2) {
            h4v hv;
            hv[0] = (_Float16)r0;
            hv[1] = (_Float16)r1;
            hv[2] = (_Float16)r2;
            hv[3] = (_Float16)r3;
            *(h4v*)op = hv;
        } else {
            *(float4*)op = make_float4(r0, r1, r2, r3);
        }
    }
}

// ---------------- launch ----------------
extern "C" void kernel_launch(void* const* d_in, const int* in_sizes, int n_in, void* d_out,
                              int out_size, void* d_ws, size_t ws_size, hipStream_t stream) {
    const float* x = (const float*)d_in[0];
    const void* ei = d_in[1];
    const float* W1 = (const float*)d_in[2];
    const float* attS1 = (const float*)d_in[3];
    const float* attD1 = (const float*)d_in[4];
    const float* b1 = (const float*)d_in[5];
    const float* W2 = (const float*)d_in[6];
    const float* attS2 = (const float*)d_in[7];
    const float* attD2 = (const float*)d_in[8];
    const float* b2 = (const float*)d_in[9];
    float* out = (float*)d_out;

    int N = in_sizes[0] / F_IN;  // 50000
    int E = in_sizes[1] / 2;     // 800000
    int nb = (N + 255) / 256;    // 196
    int nw = (N + 3) / 4;        // wave-per-node aggregate grid
    int nblk1 = (E + EB - 1) / EB;   // 391 level-1 edge blocks
    int nbuck = (N + NPB - 1) / NPB; // 196 node buckets (== nb)

    _Float16* xs_h = (_Float16*)d_ws;             // N*128
    _Float16* o1h = xs_h + (size_t)N * F_IN;      // N*256 (CSR-build scratch overlays early)
    _Float16* hb2 = o1h + (size_t)N * HC1;        // N*160
    _Float16* aggx_hi = hb2 + (size_t)N * HC2;    // N*256 (heads 2,3 of aggx)
    _Float16* B1x = aggx_hi + (size_t)N * HC1;    // 272*128
    _Float16* B2x = B1x + (HC1 + 16) * F_IN;      // 176*256
    float* as1 = (float*)(B2x + (HC2 + 16) * HC1);
    float* ad1 = as1 + (size_t)N * NHEAD;
    float* as2 = ad1 + (size_t)N * NHEAD;
    float* ad2 = as2 + (size_t)N * NHEAD;
    float* stats = ad2 + (size_t)N * NHEAD;       // 256 (zeroed in detect_kernel)
    int* offsets = (int*)(stats + 256);           // N+1 (pad 4)
    int* csr = offsets + (N + 4);                 // E+N
    int* blocksum = csr + (E + N);                // 256
    int* mode = blocksum + 256;                   // 1
    // CSR-build scratch in o1h slot (dead before gemm1b writes o1h): ~6.8MB < 25.6MB
    int* bucketEdges = (int*)o1h;                         // nbuck*BCAP (196*8192)
    int* hist = bucketEdges + (size_t)nbuck * BCAP;       // nbuck*nblk1 (bucket-major)
    int* colBaseT = hist + (size_t)nbuck * nblk1;         // nblk1*nbuck (block-major)
    int* bucketTotal = colBaseT + (size_t)nblk1 * nbuck;  // nbuck
    _Float16* aggx_lo = (_Float16*)d_out;  // heads 0,1 (25.6MB <= out buffer;
                                           // fully overwritten by final aggregate)

    constexpr int TCV = (HC1 + 16) * F_IN + (HC2 + 16) * HC1;
    int nbConv = (TCV + 255) / 256;                      // 143
    int total4 = N * F_IN / 4;
    int nbStd = (total4 + 255) / 256;                    // 6250
    int nbG1 = (N + 63) / 64;                            // 782

    // 1. detect edge dtype + zero stats
    detect_kernel<<<1, 256, 0, stream>>>((const unsigned int*)ei, mode, stats);
    // 2. fused: bucket-hist | colstats | convert_w  (no far atomics)
    fused_pre_kernel<<<nblk1 + nb + nbConv, 256, 0, stream>>>(
        ei, mode, E, nbuck, nblk1, hist, x, stats, N, W1, attS1, attD1, B1x, W2, attS2, attD2,
        B2x, nb);
    // 3. fused: standardize | bucket col-scan
    fused_mid_kernel<<<nbStd + nbuck, 256, 0, stream>>>(x, stats, xs_h, total4,
                                                        1.0f / (float)N, 1.0f / (float)(N - 1),
                                                        hist, colBaseT, bucketTotal, nbuck,
                                                        nblk1, nbStd);
    // 4. level-1 scatter into bucket regions
    scatter1_kernel<<<nblk1, 256, 0, stream>>>(ei, mode, E, nbuck, colBaseT, bucketEdges);
    // 5. fused: per-bucket node counts + block-local scan (NPB == 256 == scan block)
    bucket_count_scan_kernel<<<nbuck, 256, 0, stream>>>(bucketEdges, bucketTotal, offsets,
                                                        blocksum, N);
    // 6. scan_add (nb == nbuck == 196)
    scan_add_kernel<<<nb, 256, 0, stream>>>(blocksum, offsets, N, nb);
    // 7. fused: csr scatter | att1
    fused_csr_att1_kernel<<<nbuck + nbG1, 256, 0, stream>>>(bucketEdges, bucketTotal, offsets,
                                                            csr, N, nbuck, xs_h, B1x, as1, ad1);
    // 8. per-head aggregate in xs-space (R8 compiler-scheduled form)
    aggregate_x4_kernel<<<nw, 256, 0, stream>>>(xs_h, as1, ad1, offsets, csr, aggx_lo, aggx_hi,
                                                N);
    // 9. gemm1b: o1[:, h*64:+64] = relu(aggx[h] @ W1[:, h*64:+64] + b1)  (LDS-staged B)
    gemm1b_kernel<<<nbG1 * 2, 256, 0, stream>>>(aggx_lo, aggx_hi, B1x, b1, o1h, N);
    // 10. gemm2(+att2)  (LDS-staged B)
    gemm2_kernel<<<nbG1 * 2, 256, 0, stream>>>(o1h, B2x, hb2, as2, ad2, N);
    // 11. aggregate layer 2 (R8 compiler-scheduled form)
    aggregate_kernel<HC2, false, float>
        <<<nw, 256, 0, stream>>>(hb2, as2, ad2, offsets, csr, b2, out, N);
}